// Round 1
// baseline (323.253 us; speedup 1.0000x reference)
//
#include <hip/hip_runtime.h>

// 2D Haar DWT, single level.
// Input:  x (N=768 images of 512x512 fp32, N = 8*96)
// Output: LL | LH | HL | HH, each N x 256 x 256 fp32, concatenated.
//
// LL = 0.5(a+b+c+d)  LH = 0.5(a+b-c-d)  HL = 0.5(a-b+c-d)  HH = 0.5(a-b-c+d)
// a = x[2y,2x], b = x[2y,2x+1], c = x[2y+1,2x], d = x[2y+1,2x+1]

#define IN_W   512
#define IN_H   512
#define OUT_W  256
#define OUT_H  256

__global__ __launch_bounds__(256) void dwt2d_haar_kernel(
    const float* __restrict__ x,
    float* __restrict__ out,
    int n_img, int total)
{
    // subband strides
    const long long sub = (long long)n_img * OUT_W * OUT_H;
    float* __restrict__ ll = out;
    float* __restrict__ lh = out + sub;
    float* __restrict__ hl = out + 2 * sub;
    float* __restrict__ hh = out + 3 * sub;

    // work item t covers: image t>>15, output row (t>>7)&255, output col pair t&127
    // (per image: 256 rows * 128 col-pairs = 32768 items)
    for (int t = blockIdx.x * blockDim.x + threadIdx.x; t < total;
         t += gridDim.x * blockDim.x) {
        const int img = t >> 15;
        const int rem = t & 32767;
        const int oy  = rem >> 7;     // 0..255
        const int ox2 = rem & 127;    // col-pair 0..127

        const float* src = x + (long long)img * (IN_W * IN_H)
                             + (long long)(oy * 2) * IN_W + ox2 * 4;
        const float4 r0 = *reinterpret_cast<const float4*>(src);          // row 2y
        const float4 r1 = *reinterpret_cast<const float4*>(src + IN_W);   // row 2y+1

        float2 vll, vlh, vhl, vhh;
        // pixel 0: a=r0.x b=r0.y c=r1.x d=r1.y
        {
            const float apb = r0.x + r0.y, amb = r0.x - r0.y;
            const float cpd = r1.x + r1.y, cmd = r1.x - r1.y;
            vll.x = 0.5f * (apb + cpd);
            vlh.x = 0.5f * (apb - cpd);
            vhl.x = 0.5f * (amb + cmd);
            vhh.x = 0.5f * (amb - cmd);
        }
        // pixel 1: a=r0.z b=r0.w c=r1.z d=r1.w
        {
            const float apb = r0.z + r0.w, amb = r0.z - r0.w;
            const float cpd = r1.z + r1.w, cmd = r1.z - r1.w;
            vll.y = 0.5f * (apb + cpd);
            vlh.y = 0.5f * (apb - cpd);
            vhl.y = 0.5f * (amb + cmd);
            vhh.y = 0.5f * (amb - cmd);
        }

        const long long o = (long long)img * (OUT_W * OUT_H)
                          + (long long)oy * OUT_W + ox2 * 2;
        *reinterpret_cast<float2*>(ll + o) = vll;
        *reinterpret_cast<float2*>(lh + o) = vlh;
        *reinterpret_cast<float2*>(hl + o) = vhl;
        *reinterpret_cast<float2*>(hh + o) = vhh;
    }
}

extern "C" void kernel_launch(void* const* d_in, const int* in_sizes, int n_in,
                              void* d_out, int out_size, void* d_ws, size_t ws_size,
                              hipStream_t stream) {
    const float* x = (const float*)d_in[0];
    float* out = (float*)d_out;

    const int n_img = in_sizes[0] / (IN_W * IN_H);   // 8*96 = 768
    const int total = n_img * (OUT_H * (OUT_W / 2)); // work items (2 out cols each)

    dim3 block(256);
    dim3 grid(4096);
    dwt2d_haar_kernel<<<grid, block, 0, stream>>>(x, out, n_img, total);
}

// Round 3
// 313.539 us; speedup vs baseline: 1.0310x; 1.0310x over previous
//
#include <hip/hip_runtime.h>

// 2D Haar DWT, single level.
// Input:  x (N=768 images of 512x512 fp32, N = 8*96)
// Output: LL | LH | HL | HH, each N x 256 x 256 fp32, concatenated.
//
// LL = 0.5(a+b+c+d)  LH = 0.5(a+b-c-d)  HL = 0.5(a-b+c-d)  HH = 0.5(a-b-c+d)
// a = x[2y,2x], b = x[2y,2x+1], c = x[2y+1,2x], d = x[2y+1,2x+1]
//
// Work item = 2x8 input block -> 4 output cols in each subband.
// 4x float4 NT loads, 4x float4 NT stores (16 B/lane both directions).
// Uses clang ext_vector_type (HIP float4 is a class type that
// __builtin_nontemporal_* rejects).

#define IN_W   512
#define IN_H   512
#define OUT_W  256
#define OUT_H  256

typedef float f32x4 __attribute__((ext_vector_type(4)));

__global__ __launch_bounds__(256) void dwt2d_haar_kernel(
    const float* __restrict__ x,
    float* __restrict__ out,
    int n_img, int total)
{
    const long long sub = (long long)n_img * OUT_W * OUT_H;
    float* __restrict__ ll = out;
    float* __restrict__ lh = out + sub;
    float* __restrict__ hl = out + 2 * sub;
    float* __restrict__ hh = out + 3 * sub;

    // per image: 256 rows * 64 col-quads = 16384 items
    for (int t = blockIdx.x * blockDim.x + threadIdx.x; t < total;
         t += gridDim.x * blockDim.x) {
        const int img = t >> 14;
        const int rem = t & 16383;
        const int oy  = rem >> 6;    // 0..255
        const int ox4 = rem & 63;    // col-quad 0..63

        const float* src = x + (long long)img * (IN_W * IN_H)
                             + (long long)(oy * 2) * IN_W + ox4 * 8;
        const f32x4 r0a = __builtin_nontemporal_load(
            reinterpret_cast<const f32x4*>(src));
        const f32x4 r0b = __builtin_nontemporal_load(
            reinterpret_cast<const f32x4*>(src + 4));
        const f32x4 r1a = __builtin_nontemporal_load(
            reinterpret_cast<const f32x4*>(src + IN_W));
        const f32x4 r1b = __builtin_nontemporal_load(
            reinterpret_cast<const f32x4*>(src + IN_W + 4));

        f32x4 vll, vlh, vhl, vhh;
        // out col 0: a=r0a.x b=r0a.y c=r1a.x d=r1a.y
        {
            const float apb = r0a.x + r0a.y, amb = r0a.x - r0a.y;
            const float cpd = r1a.x + r1a.y, cmd = r1a.x - r1a.y;
            vll.x = 0.5f * (apb + cpd);
            vlh.x = 0.5f * (apb - cpd);
            vhl.x = 0.5f * (amb + cmd);
            vhh.x = 0.5f * (amb - cmd);
        }
        // out col 1: a=r0a.z b=r0a.w c=r1a.z d=r1a.w
        {
            const float apb = r0a.z + r0a.w, amb = r0a.z - r0a.w;
            const float cpd = r1a.z + r1a.w, cmd = r1a.z - r1a.w;
            vll.y = 0.5f * (apb + cpd);
            vlh.y = 0.5f * (apb - cpd);
            vhl.y = 0.5f * (amb + cmd);
            vhh.y = 0.5f * (amb - cmd);
        }
        // out col 2: a=r0b.x b=r0b.y c=r1b.x d=r1b.y
        {
            const float apb = r0b.x + r0b.y, amb = r0b.x - r0b.y;
            const float cpd = r1b.x + r1b.y, cmd = r1b.x - r1b.y;
            vll.z = 0.5f * (apb + cpd);
            vlh.z = 0.5f * (apb - cpd);
            vhl.z = 0.5f * (amb + cmd);
            vhh.z = 0.5f * (amb - cmd);
        }
        // out col 3: a=r0b.z b=r0b.w c=r1b.z d=r1b.w
        {
            const float apb = r0b.z + r0b.w, amb = r0b.z - r0b.w;
            const float cpd = r1b.z + r1b.w, cmd = r1b.z - r1b.w;
            vll.w = 0.5f * (apb + cpd);
            vlh.w = 0.5f * (apb - cpd);
            vhl.w = 0.5f * (amb + cmd);
            vhh.w = 0.5f * (amb - cmd);
        }

        const long long o = (long long)img * (OUT_W * OUT_H)
                          + (long long)oy * OUT_W + ox4 * 4;
        __builtin_nontemporal_store(vll, reinterpret_cast<f32x4*>(ll + o));
        __builtin_nontemporal_store(vlh, reinterpret_cast<f32x4*>(lh + o));
        __builtin_nontemporal_store(vhl, reinterpret_cast<f32x4*>(hl + o));
        __builtin_nontemporal_store(vhh, reinterpret_cast<f32x4*>(hh + o));
    }
}

extern "C" void kernel_launch(void* const* d_in, const int* in_sizes, int n_in,
                              void* d_out, int out_size, void* d_ws, size_t ws_size,
                              hipStream_t stream) {
    const float* x = (const float*)d_in[0];
    float* out = (float*)d_out;

    const int n_img = in_sizes[0] / (IN_W * IN_H);    // 8*96 = 768
    const int total = n_img * (OUT_H * (OUT_W / 4));  // 4 out cols per item

    dim3 block(256);
    dim3 grid(4096);
    dwt2d_haar_kernel<<<grid, block, 0, stream>>>(x, out, n_img, total);
}

// Round 4
// 280.109 us; speedup vs baseline: 1.1540x; 1.1193x over previous
//
#include <hip/hip_runtime.h>

// 2D Haar DWT, single level — LDS-staged long-burst version.
// Input:  x (768 images of 512x512 fp32)
// Output: LL | LH | HL | HH, each 768 x 256 x 256 fp32, concatenated.
//
// Block = 256 threads owns a 16-row x 512-col input tile (32 KB) of one image.
// Phase 1: coalesced float4 NT loads + horizontal butterfly -> LDS (L/H planes).
// Phase 2: vertical butterfly from LDS -> each subband written as one 8 KB
//          contiguous burst per block (float4 NT stores).
//
// LL = 0.5(sA+sB), LH = 0.5(sA-sB), HL = 0.5(dA+dB), HH = 0.5(dA-dB)
// where sA=a+b, dA=a-b (even row), sB=c+d, dB=c-d (odd row).

#define IN_W       512
#define OUT_W      256
#define TILE_IROWS 16   // input rows per block
#define TILE_OROWS 8    // output rows per block

typedef float f32x4 __attribute__((ext_vector_type(4)));
typedef float f32x2 __attribute__((ext_vector_type(2)));

__global__ __launch_bounds__(256) void dwt2d_haar_kernel(
    const float* __restrict__ x,
    float* __restrict__ out,
    int n_img)
{
    __shared__ float Lh[TILE_IROWS][OUT_W];   // 16 KB: horizontal sums  (a+b)
    __shared__ float Hh[TILE_IROWS][OUT_W];   // 16 KB: horizontal diffs (a-b)

    const int bid  = blockIdx.x;
    const int img  = bid >> 5;      // 32 tiles per image (256 out rows / 8)
    const int tile = bid & 31;
    const int tid  = threadIdx.x;

    const float* src = x + (long long)img * (IN_W * IN_W)
                         + (long long)tile * (TILE_IROWS * IN_W);

    // ---- phase 1: load 32 KB tile (coalesced float4), horizontal butterfly ----
#pragma unroll
    for (int k = 0; k < 8; ++k) {
        const int f  = tid + k * 256;   // float4 index in tile, 0..2047
        const int r  = f >> 7;          // input row within tile, 0..15
        const int c4 = f & 127;         // float4-col, 0..127
        const f32x4 v = __builtin_nontemporal_load(
            reinterpret_cast<const f32x4*>(src + (long long)f * 4));
        f32x2 s, d;
        s.x = v.x + v.y; d.x = v.x - v.y;
        s.y = v.z + v.w; d.y = v.z - v.w;
        *reinterpret_cast<f32x2*>(&Lh[r][c4 * 2]) = s;
        *reinterpret_cast<f32x2*>(&Hh[r][c4 * 2]) = d;
    }
    __syncthreads();

    // ---- phase 2: vertical butterfly, 8 KB contiguous burst per subband ----
    const long long sub = (long long)n_img * (OUT_W * OUT_W);
    float* __restrict__ ll = out;
    float* __restrict__ lh = out + sub;
    float* __restrict__ hl = out + 2 * sub;
    float* __restrict__ hh = out + 3 * sub;
    const long long obase = (long long)img * (OUT_W * OUT_W)
                          + (long long)tile * (TILE_OROWS * OUT_W);

#pragma unroll
    for (int k = 0; k < 2; ++k) {
        const int g    = tid + k * 256; // float4 index in output tile, 0..511
        const int orow = g >> 6;        // output row within tile, 0..7
        const int c4   = g & 63;        // float4-col, 0..63
        const f32x4 L0 = *reinterpret_cast<const f32x4*>(&Lh[2 * orow][c4 * 4]);
        const f32x4 L1 = *reinterpret_cast<const f32x4*>(&Lh[2 * orow + 1][c4 * 4]);
        const f32x4 H0 = *reinterpret_cast<const f32x4*>(&Hh[2 * orow][c4 * 4]);
        const f32x4 H1 = *reinterpret_cast<const f32x4*>(&Hh[2 * orow + 1][c4 * 4]);
        const long long o = obase + (long long)g * 4;
        __builtin_nontemporal_store(0.5f * (L0 + L1), reinterpret_cast<f32x4*>(ll + o));
        __builtin_nontemporal_store(0.5f * (L0 - L1), reinterpret_cast<f32x4*>(lh + o));
        __builtin_nontemporal_store(0.5f * (H0 + H1), reinterpret_cast<f32x4*>(hl + o));
        __builtin_nontemporal_store(0.5f * (H0 - H1), reinterpret_cast<f32x4*>(hh + o));
    }
}

extern "C" void kernel_launch(void* const* d_in, const int* in_sizes, int n_in,
                              void* d_out, int out_size, void* d_ws, size_t ws_size,
                              hipStream_t stream) {
    const float* x = (const float*)d_in[0];
    float* out = (float*)d_out;

    const int n_img  = in_sizes[0] / (IN_W * IN_W);  // 8*96 = 768
    const int blocks = n_img * 32;                   // 32 tiles per image

    dwt2d_haar_kernel<<<dim3(blocks), dim3(256), 0, stream>>>(x, out, n_img);
}